// Round 13
// baseline (133.582 us; speedup 1.0000x reference)
//
#include <hip/hip_runtime.h>
#include <hip/hip_bf16.h>

// Problem constants
#define B_SZ   16384
#define D_SZ   768
#define H_SZ   128
#define S_SZ   65536
#define E_SZ   7

// K layout: [0,768) h_t | [768,896) s_t | [896,1664) h_ctx | 1664..1666 sent | 1667 bias | pad->1696
// N layout: [0,256) r,z summed | [256,384) i_n | [384,512) h_n | [512,519) W_e | 519 W_s | pad->528
// Waves 0-3 COMPUTE: wave w owns hidden j in [32w,32w+32): frags r{2w,2w+1}, z{8+2w,9+2w},
//   i_n{16+2w,17+2w}, h_n{24+2w,25+2w}; heads (frag 32) K-split by (s&3)==w, LDS-reduced.
// Waves 4-7 STAGE: issue all global_load_lds DMAs + winner-copy. Per-wave vmcnt isolation
//   keeps compute waves' counted B-load waits from draining the HBM stage queue.
#define NFR    33
#define NSTEP  53

typedef __attribute__((ext_vector_type(8))) short bf16x8;
typedef __attribute__((ext_vector_type(4))) float f32x4;

#define LD4(p) (*reinterpret_cast<const float4*>(p))
#define MFMA(d, a, b) d = __builtin_amdgcn_mfma_f32_16x16x32_bf16(a, b, d, 0, 0, 0)

// async global->LDS DMA, 16B/lane, dest = wave-uniform base + lane*16
#define GLDS(gp, lp) __builtin_amdgcn_global_load_lds(                              \
        (const __attribute__((address_space(1))) unsigned int*)(gp),                \
        (__attribute__((address_space(3))) unsigned int*)(lp), 16, 0, 0)

static __device__ __forceinline__ ushort f2bf(float v) {
    unsigned u = __float_as_uint(v);
    u = (u + 0x7FFFu + ((u >> 16) & 1u)) >> 16;   // RNE (pack kernel / tail only)
    return (ushort)u;
}

static __device__ __forceinline__ unsigned pk2(float x, float y) {
    unsigned a = __float_as_uint(x) + 0x8000u;
    unsigned b = __float_as_uint(y) + 0x8000u;
    return __builtin_amdgcn_perm(b, a, 0x07060302);   // [a.hi16 | b.hi16]
}

static __device__ __forceinline__ bf16x8 cvt8(float4 a, float4 b) {
    union { unsigned u[4]; bf16x8 v; } r;
    r.u[0] = pk2(a.x, a.y); r.u[1] = pk2(a.z, a.w);
    r.u[2] = pk2(b.x, b.y); r.u[3] = pk2(b.z, b.w);
    return r.v;
}

// logical packed-weight value at (n, k)
static __device__ __forceinline__ float w2_value(int n, int k,
    const float* __restrict__ W_ih, const float* __restrict__ W_hh,
    const float* __restrict__ b_ih, const float* __restrict__ b_hh,
    const float* __restrict__ W_e,  const float* __restrict__ b_e,
    const float* __restrict__ W_s,  const float* __restrict__ b_s)
{
    float v = 0.0f;
    if (n < 256) {
        if (k < 768)                        v = W_ih[(size_t)n * 771 + k];
        else if (k < 896)                   v = W_hh[(size_t)n * 128 + (k - 768)];
        else if (k >= 1664 && k < 1667)     v = W_ih[(size_t)n * 771 + 768 + (k - 1664)];
        else if (k == 1667)                 v = b_ih[n] + b_hh[n];
    } else if (n < 384) {
        if (k < 768)                        v = W_ih[(size_t)n * 771 + k];
        else if (k >= 1664 && k < 1667)     v = W_ih[(size_t)n * 771 + 768 + (k - 1664)];
        else if (k == 1667)                 v = b_ih[n];
    } else if (n < 512) {
        int g = n - 128;
        if (k >= 768 && k < 896)            v = W_hh[(size_t)g * 128 + (k - 768)];
        else if (k == 1667)                 v = b_hh[g];
    } else if (n < 520) {
        int e = n - 512;
        const float* Wr = (e < E_SZ) ? (W_e + (size_t)e * 1667) : W_s;
        if (k < 768)                        v = Wr[k];
        else if (k < 896)                   v = Wr[771 + (k - 768)];
        else if (k < 1664)                  v = Wr[899 + (k - 896)];
        else if (k < 1667)                  v = Wr[768 + (k - 1664)];
        else if (k == 1667)                 v = (e < E_SZ) ? b_e[e] : b_s[0];
    }
    return v;
}

// ---------------- pack W2 frag-major: W2f[(nf*NSTEP + kstep)*64 + lane][8] ----------------
__global__ __launch_bounds__(256) void pack_w2f_kernel(
    const float* __restrict__ W_ih, const float* __restrict__ W_hh,
    const float* __restrict__ b_ih, const float* __restrict__ b_hh,
    const float* __restrict__ W_e,  const float* __restrict__ b_e,
    const float* __restrict__ W_s,  const float* __restrict__ b_s,
    ushort* __restrict__ W2f)
{
    int tid = blockIdx.x * 256 + threadIdx.x;
    if (tid >= NFR * NSTEP * 64) return;
    int lane  = tid & 63;
    int kstep = (tid >> 6) % NSTEP;
    int nf    = tid / (NSTEP * 64);
    int n     = nf * 16 + (lane & 15);
    int kbase = kstep * 32 + (lane >> 4) * 8;
    ushort o[8];
#pragma unroll
    for (int j = 0; j < 8; ++j)
        o[j] = f2bf(w2_value(n, kbase + j, W_ih, W_hh, b_ih, b_hh, W_e, b_e, W_s, b_s));
    *reinterpret_cast<uint4*>(W2f + (size_t)tid * 8) = *reinterpret_cast<const uint4*>(o);
}

// ---------------- winner (last-write-wins) ----------------
__global__ __launch_bounds__(256) void winner_kernel(const int* __restrict__ slot_ids,
                                                     int* __restrict__ winner)
{
    int b = blockIdx.x * 256 + threadIdx.x;
    if (b < B_SZ) atomicMax(&winner[slot_ids[b]], b);
}

static __device__ __forceinline__ bf16x8 ldB(const ushort* __restrict__ W2f, int nf, int ks, int lane) {
    return *reinterpret_cast<const bf16x8*>(W2f + ((size_t)(nf * NSTEP + ks) * 64 + lane) * 8);
}

// LDS A read: 8-step panel, XOR-swizzled (matches pre-swizzled DMA source)
static __device__ __forceinline__ float4 lds_rd(const char* Ab, int st, int row, int h) {
    return *reinterpret_cast<const float4*>(Ab + st * 4096 + row * 128 + ((h ^ (row & 7)) << 4));
}

// one GEMM K-step for wave W. KIND 0: h_t (r,z,i_n); KIND 1: s_t (r,z,h_n).
template<int W, int KIND>
static __device__ __forceinline__ void gemm_step(int s, int st, bool hd, const char* Ab, int lane,
                                                 const ushort* __restrict__ W2f,
                                                 f32x4* __restrict__ acc, f32x4* __restrict__ hacc)
{
    const int cl = lane & 15, kg = lane >> 4;
    constexpr int A4 = (KIND == 0) ? 4 : 6;
    constexpr int F4 = (KIND == 0) ? 16 : 24;
    bf16x8 B0 = ldB(W2f, 2 * W, s, lane),      B1 = ldB(W2f, 2 * W + 1, s, lane);
    bf16x8 B2 = ldB(W2f, 8 + 2 * W, s, lane),  B3 = ldB(W2f, 9 + 2 * W, s, lane);
    bf16x8 B4 = ldB(W2f, F4 + 2 * W, s, lane), B5 = ldB(W2f, F4 + 2 * W + 1, s, lane);
    bf16x8 Bh;
    if (hd) Bh = ldB(W2f, 32, s, lane);
    float4 x0 = lds_rd(Ab, st, cl, 2 * kg), x1 = lds_rd(Ab, st, cl, 2 * kg + 1);
    bf16x8 a0 = cvt8(x0, x1);
    MFMA(acc[0], a0, B0); MFMA(acc[1], a0, B1);
    MFMA(acc[2], a0, B2); MFMA(acc[3], a0, B3);
    MFMA(acc[A4], a0, B4); MFMA(acc[A4 + 1], a0, B5);
    if (hd) MFMA(hacc[0], a0, Bh);
    float4 y0 = lds_rd(Ab, st, 16 + cl, 2 * kg), y1 = lds_rd(Ab, st, 16 + cl, 2 * kg + 1);
    bf16x8 a1 = cvt8(y0, y1);
    MFMA(acc[8], a1, B0); MFMA(acc[9], a1, B1);
    MFMA(acc[10], a1, B2); MFMA(acc[11], a1, B3);
    MFMA(acc[8 + A4], a1, B4); MFMA(acc[9 + A4], a1, B5);
    if (hd) MFMA(hacc[1], a1, Bh);
}

template<int W, int C>
static __device__ __forceinline__ void chunk_ht(const char* Ab, int lane,
                                                const ushort* __restrict__ W2f,
                                                f32x4* acc, f32x4* hacc)
{
#pragma unroll
    for (int st = 0; st < 8; ++st)
        gemm_step<W, 0>(C * 8 + st, st, (st & 3) == W, Ab, lane, W2f, acc, hacc);
}

template<int W>
static __device__ __forceinline__ void chunk_st(const char* Ab, int lane,
                                                const ushort* __restrict__ W2f,
                                                f32x4* acc, f32x4* hacc)
{
#pragma unroll
    for (int t = 0; t < 4; ++t)
        gemm_step<W, 1>(24 + t, t, t == W, Ab, lane, W2f, acc, hacc);
}

// heads-only steps (h_ctx phase): wave W handles steps with (s&3)==W
template<int W, int SB, int STB, int N>
static __device__ __forceinline__ void ctx_steps(const char* Ab, int lane,
                                                 const ushort* __restrict__ W2f, f32x4* hacc)
{
    const int cl = lane & 15, kg = lane >> 4;
#pragma unroll
    for (int i = 0; i < N; ++i) {
        if (((SB + i) & 3) == W) {
            bf16x8 Bh = ldB(W2f, 32, SB + i, lane);
            float4 x0 = lds_rd(Ab, STB + i, cl, 2 * kg), x1 = lds_rd(Ab, STB + i, cl, 2 * kg + 1);
            MFMA(hacc[0], cvt8(x0, x1), Bh);
            float4 y0 = lds_rd(Ab, STB + i, 16 + cl, 2 * kg), y1 = lds_rd(Ab, STB + i, 16 + cl, 2 * kg + 1);
            MFMA(hacc[1], cvt8(y0, y1), Bh);
        }
    }
}

// tail step 52 + wave-local GRU epilogue + heads-partial dump
template<int W>
static __device__ __forceinline__ void tail_and_epilogue(
    const float* __restrict__ sent, const float* __restrict__ memory,
    const int* __restrict__ slot_ids, const int* __restrict__ winner,
    int row0, int lane, const ushort* __restrict__ W2f,
    f32x4* __restrict__ acc, f32x4* __restrict__ hacc, f32x4* __restrict__ redh,
    float* __restrict__ out_mem)
{
    const int cl = lane & 15, kg = lane >> 4;
    // tail (k=1664..1695): sent(3) + bias-one + zeros
    {
        const int rA0 = row0 + cl, rA1 = rA0 + 16;
        bf16x8 a0, a1;
#pragma unroll
        for (int jj = 0; jj < 8; ++jj) {
            int kk = kg * 8 + jj;
            float v0 = 0.f, v1 = 0.f;
            if (kk < 3)       { v0 = sent[(size_t)rA0 * 3 + kk]; v1 = sent[(size_t)rA1 * 3 + kk]; }
            else if (kk == 3) { v0 = 1.f; v1 = 1.f; }
            a0[jj] = (short)f2bf(v0); a1[jj] = (short)f2bf(v1);
        }
        bf16x8 T0 = ldB(W2f, 2 * W, 52, lane),      T1 = ldB(W2f, 2 * W + 1, 52, lane);
        bf16x8 T2 = ldB(W2f, 8 + 2 * W, 52, lane),  T3 = ldB(W2f, 9 + 2 * W, 52, lane);
        bf16x8 T4 = ldB(W2f, 16 + 2 * W, 52, lane), T5 = ldB(W2f, 17 + 2 * W, 52, lane);
        bf16x8 T6 = ldB(W2f, 24 + 2 * W, 52, lane), T7 = ldB(W2f, 25 + 2 * W, 52, lane);
        MFMA(acc[0], a0, T0); MFMA(acc[1], a0, T1);
        MFMA(acc[2], a0, T2); MFMA(acc[3], a0, T3);
        MFMA(acc[4], a0, T4); MFMA(acc[5], a0, T5);
        MFMA(acc[6], a0, T6); MFMA(acc[7], a0, T7);
        MFMA(acc[8], a1, T0); MFMA(acc[9], a1, T1);
        MFMA(acc[10], a1, T2); MFMA(acc[11], a1, T3);
        MFMA(acc[12], a1, T4); MFMA(acc[13], a1, T5);
        MFMA(acc[14], a1, T6); MFMA(acc[15], a1, T7);
        if constexpr (W == 0) {   // step 52: (52&3)==0
            bf16x8 Bh = ldB(W2f, 32, 52, lane);
            MFMA(hacc[0], a0, Bh); MFMA(hacc[1], a1, Bh);
        }
    }
    // dump heads partials (read after the following barrier)
    redh[(0 * 4 + W) * 64 + lane] = hacc[0];
    redh[(1 * 4 + W) * 64 + lane] = hacc[1];
    // wave-local GRU + winner scatter for hidden j in [32W, 32W+32)
#pragma unroll
    for (int rg = 0; rg < 2; ++rg) {
#pragma unroll
        for (int r = 0; r < 4; ++r) {
            const int row  = row0 + rg * 16 + kg * 4 + r;
            const int slot = slot_ids[row];
            const bool win = (winner[slot] == row);
#pragma unroll
            for (int jb = 0; jb < 2; ++jb) {
                const int j = 32 * W + jb * 16 + cl;
                float rgate = acc[rg * 8 + jb][r];
                float zg    = acc[rg * 8 + 2 + jb][r];
                float inn   = acc[rg * 8 + 4 + jb][r];
                float hnn   = acc[rg * 8 + 6 + jb][r];
                rgate = 1.0f / (1.0f + __expf(-rgate));
                zg    = 1.0f / (1.0f + __expf(-zg));
                float nn = tanhf(inn + rgate * hnn);
                float h  = memory[(size_t)slot * H_SZ + j];   // exact f32 pre-update state
                float sn = (1.0f - zg) * nn + zg * h;
                if (win) out_mem[(size_t)slot * H_SZ + j] = sn;
            }
        }
    }
}

// ---------------- fused kernel: 4 compute waves + 4 stage waves ----------------
__global__ __launch_bounds__(512, 2) void fused_kernel(
    const float* __restrict__ h_t,   const float* __restrict__ h_ctx,
    const float* __restrict__ sent,  const int* __restrict__ slot_ids,
    const float* __restrict__ memory,const ushort* __restrict__ W2f,
    const int* __restrict__ winner,
    float* __restrict__ out_emo, float* __restrict__ out_shift, float* __restrict__ out_mem)
{
    __shared__ alignas(16) char  A_st[2][8 * 4096];   // 64 KB: 2 bufs x 8 steps x [32 rows][128 B]
    __shared__ alignas(16) f32x4 redh[8 * 64];        // 8 KB heads partials

    const int tid  = threadIdx.x;
    const int wave = tid >> 6;
    const int lane = tid & 63;
    const int row0 = blockIdx.x * 32;
    const bool is_stage = (wave >= 4);
    const int  sw   = wave & 3;                       // stage-wave index

    // staging identity (stage waves): stid -> (row = stid>>3, lds-chunk = stid&7), pre-swizzled src
    const int stid  = tid & 255;
    const int srow  = stid >> 3;
    const int scg   = (stid & 7) ^ (srow & 7);
    const int sslot = is_stage ? slot_ids[row0 + srow] : 0;

    f32x4 acc[16], hacc[2];
    {
        f32x4 z = {0.f, 0.f, 0.f, 0.f};
#pragma unroll
        for (int i = 0; i < 16; ++i) acc[i] = z;
        hacc[0] = z; hacc[1] = z;
    }

#define STAGE_HT(BUF, S0) do { _Pragma("unroll")                                          \
    for (int st = 0; st < 8; ++st)                                                        \
        GLDS(h_t + (size_t)(row0 + srow) * D_SZ + (S0 + st) * 32 + scg * 4,               \
             &A_st[BUF][st * 4096 + sw * 1024]); } while (0)

#define STAGE_MEM(BUF) do { _Pragma("unroll")                                             \
    for (int st = 0; st < 4; ++st)                                                        \
        GLDS(memory + (size_t)sslot * H_SZ + st * 32 + scg * 4,                           \
             &A_st[BUF][st * 4096 + sw * 1024]); } while (0)

#define STAGE_CTX(BUF, X0, STB, N) do { _Pragma("unroll")                                 \
    for (int st = 0; st < (N); ++st)                                                      \
        GLDS(h_ctx + (size_t)(row0 + srow) * D_SZ + ((X0) + st) * 32 + scg * 4,           \
             &A_st[BUF][((STB) + st) * 4096 + sw * 1024]); } while (0)

#define COPYSL(I0, N) do {                                                                \
    for (int k = 0; k < (N); ++k) {                                                       \
        int idx  = ((I0) + k) * 256 + stid;                                               \
        int rr   = idx >> 5;                                                              \
        int c4   = (idx & 31) * 4;                                                        \
        int slot = blockIdx.x * 128 + rr;                                                 \
        if (winner[slot] < 0) {                                                           \
            float4 v = LD4(memory + (size_t)slot * H_SZ + c4);                            \
            *reinterpret_cast<float4*>(out_mem + (size_t)slot * H_SZ + c4) = v;           \
        } } } while (0)

#define BYWAVE(...) do { switch (wave) {                                                  \
    case 0: { constexpr int W = 0; __VA_ARGS__; } break;                                  \
    case 1: { constexpr int W = 1; __VA_ARGS__; } break;                                  \
    case 2: { constexpr int W = 2; __VA_ARGS__; } break;                                  \
    default:{ constexpr int W = 3; __VA_ARGS__; } break; } } while (0)

    // prologue: stage chunk 0 (h_t steps 0-7)
    if (is_stage) STAGE_HT(0, 0);
    __syncthreads();

    // iter 0: compute chunk 0 (buf0) || stage chunk 1 (buf1)
    if (is_stage) { STAGE_HT(1, 8); COPYSL(0, 3); }
    else BYWAVE(chunk_ht<W, 0>(A_st[0], lane, W2f, acc, hacc));
    __syncthreads();

    // iter 1: chunk 1 (buf1) || stage chunk 2
    if (is_stage) { STAGE_HT(0, 16); COPYSL(3, 3); }
    else BYWAVE(chunk_ht<W, 1>(A_st[1], lane, W2f, acc, hacc));
    __syncthreads();

    // iter 2: chunk 2 (buf0) || stage chunk 3 (4 s_t gather + ctx 28-31)
    if (is_stage) { STAGE_MEM(1); STAGE_CTX(1, 0, 4, 4); COPYSL(6, 2); }
    else BYWAVE(chunk_ht<W, 2>(A_st[0], lane, W2f, acc, hacc));
    __syncthreads();

    // iter 3: chunk 3 (buf1) || stage chunk 4 (ctx 32-39)
    if (is_stage) { STAGE_CTX(0, 4, 0, 8); COPYSL(8, 2); }
    else BYWAVE((chunk_st<W>(A_st[1], lane, W2f, acc, hacc),
                 ctx_steps<W, 28, 4, 4>(A_st[1], lane, W2f, hacc)));
    __syncthreads();

    // iter 4: chunk 4 (buf0) || stage chunk 5 (ctx 40-47)
    if (is_stage) { STAGE_CTX(1, 12, 0, 8); COPYSL(10, 2); }
    else BYWAVE((ctx_steps<W, 32, 0, 8>(A_st[0], lane, W2f, hacc)));
    __syncthreads();

    // iter 5: chunk 5 (buf1) || stage chunk 6 (ctx 48-51)
    if (is_stage) { STAGE_CTX(0, 20, 0, 4); COPYSL(12, 2); }
    else BYWAVE((ctx_steps<W, 40, 0, 8>(A_st[1], lane, W2f, hacc)));
    __syncthreads();

    // iter 6: chunk 6 (buf0) + tail + wave-local GRU + heads dump || copy tail
    if (is_stage) { COPYSL(14, 2); }
    else BYWAVE((ctx_steps<W, 48, 0, 4>(A_st[0], lane, W2f, hacc),
                 tail_and_epilogue<W>(sent, memory, slot_ids, winner, row0, lane, W2f,
                                      acc, hacc, redh, out_mem)));
    __syncthreads();

    // heads outputs: sum 4 compute waves' partials
    if (tid < 128) {
        const int rg = tid >> 6, l = tid & 63;
        f32x4 hv = redh[(rg * 4 + 0) * 64 + l];
        hv += redh[(rg * 4 + 1) * 64 + l];
        hv += redh[(rg * 4 + 2) * 64 + l];
        hv += redh[(rg * 4 + 3) * 64 + l];
        const int col  = l & 15;
        const int rowb = row0 + rg * 16 + (l >> 4) * 4;
#pragma unroll
        for (int r = 0; r < 4; ++r) {
            const int row = rowb + r;
            if (col < E_SZ)       out_emo[(size_t)row * E_SZ + col] = hv[r];
            else if (col == E_SZ) out_shift[row] = hv[r];
        }
    }
#undef STAGE_HT
#undef STAGE_MEM
#undef STAGE_CTX
#undef COPYSL
#undef BYWAVE
}

// ---------------- launch ----------------
extern "C" void kernel_launch(void* const* d_in, const int* in_sizes, int n_in,
                              void* d_out, int out_size, void* d_ws, size_t ws_size,
                              hipStream_t stream)
{
    const float* h_t     = (const float*)d_in[0];
    const float* h_ctx   = (const float*)d_in[1];
    const float* sent    = (const float*)d_in[2];
    const int*   slot_ids= (const int*)  d_in[3];
    const float* memory  = (const float*)d_in[4];
    const float* W_ih    = (const float*)d_in[5];
    const float* W_hh    = (const float*)d_in[6];
    const float* b_ih    = (const float*)d_in[7];
    const float* b_hh    = (const float*)d_in[8];
    const float* W_e     = (const float*)d_in[9];
    const float* b_e     = (const float*)d_in[10];
    const float* W_s     = (const float*)d_in[11];
    const float* b_s     = (const float*)d_in[12];

    float* out       = (float*)d_out;
    float* out_emo   = out;                                    // [B,7]
    float* out_shift = out + (size_t)B_SZ * E_SZ;              // [B]
    float* out_mem   = out + (size_t)B_SZ * E_SZ + B_SZ;       // [S,H]

    int*    winner = (int*)d_ws;                               // S ints
    ushort* W2f    = (ushort*)((char*)d_ws + (size_t)S_SZ * sizeof(int));

    hipMemsetAsync(winner, 0xFF, (size_t)S_SZ * sizeof(int), stream);   // -1

    pack_w2f_kernel<<<(NFR * NSTEP * 64 + 255) / 256, 256, 0, stream>>>(
        W_ih, W_hh, b_ih, b_hh, W_e, b_e, W_s, b_s, W2f);
    winner_kernel<<<B_SZ / 256, 256, 0, stream>>>(slot_ids, winner);
    fused_kernel<<<B_SZ / 32, 512, 0, stream>>>(
        h_t, h_ctx, sent, slot_ids, memory, W2f, winner, out_emo, out_shift, out_mem);
}

// Round 15
// 90.076 us; speedup vs baseline: 1.4830x; 1.4830x over previous
//
#include <hip/hip_runtime.h>
#include <hip/hip_bf16.h>

// Problem constants
#define B_SZ   16384
#define D_SZ   768
#define H_SZ   128
#define S_SZ   65536
#define E_SZ   7

// K layout: [0,768) h_t | [768,896) s_t | [896,1664) h_ctx | 1664..1666 sent | 1667 bias | pad->1696
// N layout: [0,256) r,z summed | [256,384) i_n | [384,512) h_n | [512,519) W_e | 519 W_s | pad->528
// Wave w owns hidden j in [32w, 32w+32): frags r {2w,2w+1}, z {8+2w,9+2w}, i_n {16+2w,17+2w},
// h_n {24+2w,25+2w} -> GRU epilogue is wave-local. Heads (frag 32) K-split by (s&3)==w, LDS-reduced.
// A staged in 8-step chunks (32 KB) via global_load_lds, double-buffered.
// ITER ORDER = {compute, copy, stage, barrier}: keeps stage DMAs NEWEST in each wave's vmcnt
// queue so B-load waits during compute never drain them (round-12 had stage first = serialized).
#define NFR    33
#define NSTEP  53

typedef __attribute__((ext_vector_type(8))) short bf16x8;
typedef __attribute__((ext_vector_type(4))) float f32x4;

#define LD4(p) (*reinterpret_cast<const float4*>(p))
#define MFMA(d, a, b) d = __builtin_amdgcn_mfma_f32_16x16x32_bf16(a, b, d, 0, 0, 0)

// async global->LDS DMA, 16B/lane, dest = wave-uniform base + lane*16
#define GLDS(gp, lp) __builtin_amdgcn_global_load_lds(                              \
        (const __attribute__((address_space(1))) unsigned int*)(gp),                \
        (__attribute__((address_space(3))) unsigned int*)(lp), 16, 0, 0)

static __device__ __forceinline__ ushort f2bf(float v) {
    unsigned u = __float_as_uint(v);
    u = (u + 0x7FFFu + ((u >> 16) & 1u)) >> 16;   // RNE (pack kernel / tail only)
    return (ushort)u;
}

static __device__ __forceinline__ unsigned pk2(float x, float y) {
    unsigned a = __float_as_uint(x) + 0x8000u;
    unsigned b = __float_as_uint(y) + 0x8000u;
    return __builtin_amdgcn_perm(b, a, 0x07060302);   // [a.hi16 | b.hi16]
}

static __device__ __forceinline__ bf16x8 cvt8(float4 a, float4 b) {
    union { unsigned u[4]; bf16x8 v; } r;
    r.u[0] = pk2(a.x, a.y); r.u[1] = pk2(a.z, a.w);
    r.u[2] = pk2(b.x, b.y); r.u[3] = pk2(b.z, b.w);
    return r.v;
}

// logical packed-weight value at (n, k)
static __device__ __forceinline__ float w2_value(int n, int k,
    const float* __restrict__ W_ih, const float* __restrict__ W_hh,
    const float* __restrict__ b_ih, const float* __restrict__ b_hh,
    const float* __restrict__ W_e,  const float* __restrict__ b_e,
    const float* __restrict__ W_s,  const float* __restrict__ b_s)
{
    float v = 0.0f;
    if (n < 256) {
        if (k < 768)                        v = W_ih[(size_t)n * 771 + k];
        else if (k < 896)                   v = W_hh[(size_t)n * 128 + (k - 768)];
        else if (k >= 1664 && k < 1667)     v = W_ih[(size_t)n * 771 + 768 + (k - 1664)];
        else if (k == 1667)                 v = b_ih[n] + b_hh[n];
    } else if (n < 384) {
        if (k < 768)                        v = W_ih[(size_t)n * 771 + k];
        else if (k >= 1664 && k < 1667)     v = W_ih[(size_t)n * 771 + 768 + (k - 1664)];
        else if (k == 1667)                 v = b_ih[n];
    } else if (n < 512) {
        int g = n - 128;
        if (k >= 768 && k < 896)            v = W_hh[(size_t)g * 128 + (k - 768)];
        else if (k == 1667)                 v = b_hh[g];
    } else if (n < 520) {
        int e = n - 512;
        const float* Wr = (e < E_SZ) ? (W_e + (size_t)e * 1667) : W_s;
        if (k < 768)                        v = Wr[k];
        else if (k < 896)                   v = Wr[771 + (k - 768)];
        else if (k < 1664)                  v = Wr[899 + (k - 896)];
        else if (k < 1667)                  v = Wr[768 + (k - 1664)];
        else if (k == 1667)                 v = (e < E_SZ) ? b_e[e] : b_s[0];
    }
    return v;
}

// ---------------- pack W2 frag-major: W2f[(nf*NSTEP + kstep)*64 + lane][8] ----------------
__global__ __launch_bounds__(256) void pack_w2f_kernel(
    const float* __restrict__ W_ih, const float* __restrict__ W_hh,
    const float* __restrict__ b_ih, const float* __restrict__ b_hh,
    const float* __restrict__ W_e,  const float* __restrict__ b_e,
    const float* __restrict__ W_s,  const float* __restrict__ b_s,
    ushort* __restrict__ W2f)
{
    int tid = blockIdx.x * 256 + threadIdx.x;
    if (tid >= NFR * NSTEP * 64) return;
    int lane  = tid & 63;
    int kstep = (tid >> 6) % NSTEP;
    int nf    = tid / (NSTEP * 64);
    int n     = nf * 16 + (lane & 15);
    int kbase = kstep * 32 + (lane >> 4) * 8;
    ushort o[8];
#pragma unroll
    for (int j = 0; j < 8; ++j)
        o[j] = f2bf(w2_value(n, kbase + j, W_ih, W_hh, b_ih, b_hh, W_e, b_e, W_s, b_s));
    *reinterpret_cast<uint4*>(W2f + (size_t)tid * 8) = *reinterpret_cast<const uint4*>(o);
}

// ---------------- winner (last-write-wins) ----------------
__global__ __launch_bounds__(256) void winner_kernel(const int* __restrict__ slot_ids,
                                                     int* __restrict__ winner)
{
    int b = blockIdx.x * 256 + threadIdx.x;
    if (b < B_SZ) atomicMax(&winner[slot_ids[b]], b);
}

static __device__ __forceinline__ bf16x8 ldB(const ushort* __restrict__ W2f, int nf, int ks, int lane) {
    return *reinterpret_cast<const bf16x8*>(W2f + ((size_t)(nf * NSTEP + ks) * 64 + lane) * 8);
}

// LDS A read: 8-step panel, XOR-swizzled (matches pre-swizzled DMA source)
static __device__ __forceinline__ float4 lds_rd(const char* Ab, int st, int row, int h) {
    return *reinterpret_cast<const float4*>(Ab + st * 4096 + row * 128 + ((h ^ (row & 7)) << 4));
}

// one GEMM K-step for wave W. KIND 0: h_t (r,z,i_n); KIND 1: s_t (r,z,h_n).
template<int W, int KIND>
static __device__ __forceinline__ void gemm_step(int s, int st, bool hd, const char* Ab, int lane,
                                                 const ushort* __restrict__ W2f,
                                                 f32x4* __restrict__ acc, f32x4* __restrict__ hacc)
{
    const int cl = lane & 15, kg = lane >> 4;
    constexpr int A4 = (KIND == 0) ? 4 : 6;
    constexpr int F4 = (KIND == 0) ? 16 : 24;
    bf16x8 B0 = ldB(W2f, 2 * W, s, lane),      B1 = ldB(W2f, 2 * W + 1, s, lane);
    bf16x8 B2 = ldB(W2f, 8 + 2 * W, s, lane),  B3 = ldB(W2f, 9 + 2 * W, s, lane);
    bf16x8 B4 = ldB(W2f, F4 + 2 * W, s, lane), B5 = ldB(W2f, F4 + 2 * W + 1, s, lane);
    bf16x8 Bh;
    if (hd) Bh = ldB(W2f, 32, s, lane);
    float4 x0 = lds_rd(Ab, st, cl, 2 * kg), x1 = lds_rd(Ab, st, cl, 2 * kg + 1);
    bf16x8 a0 = cvt8(x0, x1);
    MFMA(acc[0], a0, B0); MFMA(acc[1], a0, B1);
    MFMA(acc[2], a0, B2); MFMA(acc[3], a0, B3);
    MFMA(acc[A4], a0, B4); MFMA(acc[A4 + 1], a0, B5);
    if (hd) MFMA(hacc[0], a0, Bh);
    float4 y0 = lds_rd(Ab, st, 16 + cl, 2 * kg), y1 = lds_rd(Ab, st, 16 + cl, 2 * kg + 1);
    bf16x8 a1 = cvt8(y0, y1);
    MFMA(acc[8], a1, B0); MFMA(acc[9], a1, B1);
    MFMA(acc[10], a1, B2); MFMA(acc[11], a1, B3);
    MFMA(acc[8 + A4], a1, B4); MFMA(acc[9 + A4], a1, B5);
    if (hd) MFMA(hacc[1], a1, Bh);
}

template<int W, int C>
static __device__ __forceinline__ void chunk_ht(const char* Ab, int lane,
                                                const ushort* __restrict__ W2f,
                                                f32x4* acc, f32x4* hacc)
{
#pragma unroll
    for (int st = 0; st < 8; ++st)
        gemm_step<W, 0>(C * 8 + st, st, (st & 3) == W, Ab, lane, W2f, acc, hacc);
}

template<int W>
static __device__ __forceinline__ void chunk_st(const char* Ab, int lane,
                                                const ushort* __restrict__ W2f,
                                                f32x4* acc, f32x4* hacc)
{
#pragma unroll
    for (int t = 0; t < 4; ++t)
        gemm_step<W, 1>(24 + t, t, t == W, Ab, lane, W2f, acc, hacc);
}

// heads-only steps (h_ctx phase): wave W handles steps with (s&3)==W
template<int W, int SB, int STB, int N>
static __device__ __forceinline__ void ctx_steps(const char* Ab, int lane,
                                                 const ushort* __restrict__ W2f, f32x4* hacc)
{
    const int cl = lane & 15, kg = lane >> 4;
#pragma unroll
    for (int i = 0; i < N; ++i) {
        if (((SB + i) & 3) == W) {
            bf16x8 Bh = ldB(W2f, 32, SB + i, lane);
            float4 x0 = lds_rd(Ab, STB + i, cl, 2 * kg), x1 = lds_rd(Ab, STB + i, cl, 2 * kg + 1);
            MFMA(hacc[0], cvt8(x0, x1), Bh);
            float4 y0 = lds_rd(Ab, STB + i, 16 + cl, 2 * kg), y1 = lds_rd(Ab, STB + i, 16 + cl, 2 * kg + 1);
            MFMA(hacc[1], cvt8(y0, y1), Bh);
        }
    }
}

// tail step 52 + wave-local GRU epilogue + heads-partial dump
template<int W>
static __device__ __forceinline__ void tail_and_epilogue(
    const float* __restrict__ sent, const float* __restrict__ memory,
    const int* __restrict__ slot_ids, const int* __restrict__ winner,
    int row0, int lane, const ushort* __restrict__ W2f,
    f32x4* __restrict__ acc, f32x4* __restrict__ hacc, f32x4* __restrict__ redh,
    float* __restrict__ out_mem)
{
    const int cl = lane & 15, kg = lane >> 4;
    // tail (k=1664..1695): sent(3) + bias-one + zeros
    {
        const int rA0 = row0 + cl, rA1 = rA0 + 16;
        bf16x8 a0, a1;
#pragma unroll
        for (int jj = 0; jj < 8; ++jj) {
            int kk = kg * 8 + jj;
            float v0 = 0.f, v1 = 0.f;
            if (kk < 3)       { v0 = sent[(size_t)rA0 * 3 + kk]; v1 = sent[(size_t)rA1 * 3 + kk]; }
            else if (kk == 3) { v0 = 1.f; v1 = 1.f; }
            a0[jj] = (short)f2bf(v0); a1[jj] = (short)f2bf(v1);
        }
        bf16x8 T0 = ldB(W2f, 2 * W, 52, lane),      T1 = ldB(W2f, 2 * W + 1, 52, lane);
        bf16x8 T2 = ldB(W2f, 8 + 2 * W, 52, lane),  T3 = ldB(W2f, 9 + 2 * W, 52, lane);
        bf16x8 T4 = ldB(W2f, 16 + 2 * W, 52, lane), T5 = ldB(W2f, 17 + 2 * W, 52, lane);
        bf16x8 T6 = ldB(W2f, 24 + 2 * W, 52, lane), T7 = ldB(W2f, 25 + 2 * W, 52, lane);
        MFMA(acc[0], a0, T0); MFMA(acc[1], a0, T1);
        MFMA(acc[2], a0, T2); MFMA(acc[3], a0, T3);
        MFMA(acc[4], a0, T4); MFMA(acc[5], a0, T5);
        MFMA(acc[6], a0, T6); MFMA(acc[7], a0, T7);
        MFMA(acc[8], a1, T0); MFMA(acc[9], a1, T1);
        MFMA(acc[10], a1, T2); MFMA(acc[11], a1, T3);
        MFMA(acc[12], a1, T4); MFMA(acc[13], a1, T5);
        MFMA(acc[14], a1, T6); MFMA(acc[15], a1, T7);
        if constexpr (W == 0) {   // step 52: (52&3)==0
            bf16x8 Bh = ldB(W2f, 32, 52, lane);
            MFMA(hacc[0], a0, Bh); MFMA(hacc[1], a1, Bh);
        }
    }
    // dump heads partials (read after the following barrier)
    redh[(0 * 4 + W) * 64 + lane] = hacc[0];
    redh[(1 * 4 + W) * 64 + lane] = hacc[1];
    // wave-local GRU + winner scatter for hidden j in [32W, 32W+32)
#pragma unroll
    for (int rg = 0; rg < 2; ++rg) {
#pragma unroll
        for (int r = 0; r < 4; ++r) {
            const int row  = row0 + rg * 16 + kg * 4 + r;
            const int slot = slot_ids[row];
            const bool win = (winner[slot] == row);
#pragma unroll
            for (int jb = 0; jb < 2; ++jb) {
                const int j = 32 * W + jb * 16 + cl;
                float rgate = acc[rg * 8 + jb][r];
                float zg    = acc[rg * 8 + 2 + jb][r];
                float inn   = acc[rg * 8 + 4 + jb][r];
                float hnn   = acc[rg * 8 + 6 + jb][r];
                rgate = 1.0f / (1.0f + __expf(-rgate));
                zg    = 1.0f / (1.0f + __expf(-zg));
                float nn = tanhf(inn + rgate * hnn);
                float h  = memory[(size_t)slot * H_SZ + j];   // exact f32 pre-update state
                float sn = (1.0f - zg) * nn + zg * h;
                if (win) out_mem[(size_t)slot * H_SZ + j] = sn;
            }
        }
    }
}

// ---------------- fused kernel ----------------
__global__ __launch_bounds__(256, 2) void fused_kernel(
    const float* __restrict__ h_t,   const float* __restrict__ h_ctx,
    const float* __restrict__ sent,  const int* __restrict__ slot_ids,
    const float* __restrict__ memory,const ushort* __restrict__ W2f,
    const int* __restrict__ winner,
    float* __restrict__ out_emo, float* __restrict__ out_shift, float* __restrict__ out_mem)
{
    __shared__ alignas(16) char  A_st[2][8 * 4096];   // 64 KB: 2 bufs x 8 steps x [32 rows][128 B]
    __shared__ alignas(16) f32x4 redh[8 * 64];        // 8 KB heads partials

    const int tid  = threadIdx.x;
    const int wave = tid >> 6;
    const int lane = tid & 63;
    const int row0 = blockIdx.x * 32;

    // staging identity: thread -> (row = tid>>3, lds-chunk = tid&7); global chunk pre-swizzled
    const int srow  = tid >> 3;
    const int scg   = (tid & 7) ^ (srow & 7);
    const int sslot = slot_ids[row0 + srow];

    f32x4 acc[16], hacc[2];
    {
        f32x4 z = {0.f, 0.f, 0.f, 0.f};
#pragma unroll
        for (int i = 0; i < 16; ++i) acc[i] = z;
        hacc[0] = z; hacc[1] = z;
    }

#define STAGE_HT(BUF, S0) do { _Pragma("unroll")                                          \
    for (int st = 0; st < 8; ++st)                                                        \
        GLDS(h_t + (size_t)(row0 + srow) * D_SZ + (S0 + st) * 32 + scg * 4,               \
             &A_st[BUF][st * 4096 + wave * 1024]); } while (0)

#define STAGE_MEM(BUF) do { _Pragma("unroll")                                             \
    for (int st = 0; st < 4; ++st)                                                        \
        GLDS(memory + (size_t)sslot * H_SZ + st * 32 + scg * 4,                           \
             &A_st[BUF][st * 4096 + wave * 1024]); } while (0)

#define STAGE_CTX(BUF, X0, STB, N) do { _Pragma("unroll")                                 \
    for (int st = 0; st < (N); ++st)                                                      \
        GLDS(h_ctx + (size_t)(row0 + srow) * D_SZ + ((X0) + st) * 32 + scg * 4,           \
             &A_st[BUF][((STB) + st) * 4096 + wave * 1024]); } while (0)

#define COPYSL(I0, N) do {                                                                \
    for (int k = 0; k < (N); ++k) {                                                       \
        int idx  = ((I0) + k) * 256 + tid;                                                \
        int rr   = idx >> 5;                                                              \
        int c4   = (idx & 31) * 4;                                                        \
        int slot = blockIdx.x * 128 + rr;                                                 \
        if (winner[slot] < 0) {                                                           \
            float4 v = LD4(memory + (size_t)slot * H_SZ + c4);                            \
            *reinterpret_cast<float4*>(out_mem + (size_t)slot * H_SZ + c4) = v;           \
        } } } while (0)

#define BYWAVE(...) do { switch (wave) {                                                  \
    case 0: { constexpr int W = 0; __VA_ARGS__; } break;                                  \
    case 1: { constexpr int W = 1; __VA_ARGS__; } break;                                  \
    case 2: { constexpr int W = 2; __VA_ARGS__; } break;                                  \
    default:{ constexpr int W = 3; __VA_ARGS__; } break; } } while (0)

    // prologue: stage chunk 0 (h_t steps 0-7)
    STAGE_HT(0, 0);
    __syncthreads();

    // Iter order: COMPUTE -> COPY -> STAGE(next) -> barrier.
    // Compute's B-load vmcnt waits never drain stage DMAs (DMAs are newest);
    // barrier's vmcnt(0) drains the stage, covered by the co-resident block.

    // iter 0: compute chunk 0 (buf0); stage chunk 1 (buf1)
    BYWAVE(chunk_ht<W, 0>(A_st[0], lane, W2f, acc, hacc));
    COPYSL(0, 3);
    STAGE_HT(1, 8);
    __syncthreads();

    // iter 1: compute chunk 1 (buf1); stage chunk 2 (buf0)
    BYWAVE(chunk_ht<W, 1>(A_st[1], lane, W2f, acc, hacc));
    COPYSL(3, 3);
    STAGE_HT(0, 16);
    __syncthreads();

    // iter 2: compute chunk 2 (buf0); stage chunk 3 (4 s_t gather + ctx 28-31 -> buf1)
    BYWAVE(chunk_ht<W, 2>(A_st[0], lane, W2f, acc, hacc));
    COPYSL(6, 2);
    STAGE_MEM(1); STAGE_CTX(1, 0, 4, 4);
    __syncthreads();

    // iter 3: compute chunk 3 (buf1: s_t + ctx 28-31); stage chunk 4 (ctx 32-39 -> buf0)
    BYWAVE((chunk_st<W>(A_st[1], lane, W2f, acc, hacc),
            ctx_steps<W, 28, 4, 4>(A_st[1], lane, W2f, hacc)));
    COPYSL(8, 2);
    STAGE_CTX(0, 4, 0, 8);
    __syncthreads();

    // iter 4: compute chunk 4 (buf0: ctx 32-39); stage chunk 5 (ctx 40-47 -> buf1)
    BYWAVE((ctx_steps<W, 32, 0, 8>(A_st[0], lane, W2f, hacc)));
    COPYSL(10, 2);
    STAGE_CTX(1, 12, 0, 8);
    __syncthreads();

    // iter 5: compute chunk 5 (buf1: ctx 40-47); stage chunk 6 (ctx 48-51 -> buf0)
    BYWAVE((ctx_steps<W, 40, 0, 8>(A_st[1], lane, W2f, hacc)));
    COPYSL(12, 2);
    STAGE_CTX(0, 20, 0, 4);
    __syncthreads();

    // iter 6: compute chunk 6 (buf0: ctx 48-51) + tail + wave-local GRU + heads dump
    BYWAVE((ctx_steps<W, 48, 0, 4>(A_st[0], lane, W2f, hacc),
            tail_and_epilogue<W>(sent, memory, slot_ids, winner, row0, lane, W2f,
                                 acc, hacc, redh, out_mem)));
    COPYSL(14, 2);
    __syncthreads();

    // heads outputs: sum 4 waves' partials
    if (tid < 128) {
        const int rg = tid >> 6, l = tid & 63;
        f32x4 hv = redh[(rg * 4 + 0) * 64 + l];
        hv += redh[(rg * 4 + 1) * 64 + l];
        hv += redh[(rg * 4 + 2) * 64 + l];
        hv += redh[(rg * 4 + 3) * 64 + l];
        const int col  = l & 15;
        const int rowb = row0 + rg * 16 + (l >> 4) * 4;
#pragma unroll
        for (int r = 0; r < 4; ++r) {
            const int row = rowb + r;
            if (col < E_SZ)       out_emo[(size_t)row * E_SZ + col] = hv[r];
            else if (col == E_SZ) out_shift[row] = hv[r];
        }
    }
#undef STAGE_HT
#undef STAGE_MEM
#undef STAGE_CTX
#undef COPYSL
#undef BYWAVE
}

// ---------------- launch ----------------
extern "C" void kernel_launch(void* const* d_in, const int* in_sizes, int n_in,
                              void* d_out, int out_size, void* d_ws, size_t ws_size,
                              hipStream_t stream)
{
    const float* h_t     = (const float*)d_in[0];
    const float* h_ctx   = (const float*)d_in[1];
    const float* sent    = (const float*)d_in[2];
    const int*   slot_ids= (const int*)  d_in[3];
    const float* memory  = (const float*)d_in[4];
    const float* W_ih    = (const float*)d_in[5];
    const float* W_hh    = (const float*)d_in[6];
    const float* b_ih    = (const float*)d_in[7];
    const float* b_hh    = (const float*)d_in[8];
    const float* W_e     = (const float*)d_in[9];
    const float* b_e     = (const float*)d_in[10];
    const float* W_s     = (const float*)d_in[11];
    const float* b_s     = (const float*)d_in[12];

    float* out       = (float*)d_out;
    float* out_emo   = out;                                    // [B,7]
    float* out_shift = out + (size_t)B_SZ * E_SZ;              // [B]
    float* out_mem   = out + (size_t)B_SZ * E_SZ + B_SZ;       // [S,H]

    int*    winner = (int*)d_ws;                               // S ints
    ushort* W2f    = (ushort*)((char*)d_ws + (size_t)S_SZ * sizeof(int));

    hipMemsetAsync(winner, 0xFF, (size_t)S_SZ * sizeof(int), stream);   // -1

    pack_w2f_kernel<<<(NFR * NSTEP * 64 + 255) / 256, 256, 0, stream>>>(
        W_ih, W_hh, b_ih, b_hh, W_e, b_e, W_s, b_s, W2f);
    winner_kernel<<<B_SZ / 256, 256, 0, stream>>>(slot_ids, winner);
    fused_kernel<<<B_SZ / 32, 256, 0, stream>>>(
        h_t, h_ctx, sent, slot_ids, memory, W2f, winner, out_emo, out_shift, out_mem);
}

// Round 16
// 77.162 us; speedup vs baseline: 1.7312x; 1.1674x over previous
//
#include <hip/hip_runtime.h>
#include <hip/hip_bf16.h>

// Problem constants
#define B_SZ   16384
#define D_SZ   768
#define H_SZ   128
#define S_SZ   65536
#define E_SZ   7

// K layout: [0,768) h_t | [768,896) s_t | [896,1664) h_ctx | 1664..1666 sent | 1667 bias | pad->1696
// N layout: [0,256) r,z summed | [256,384) i_n | [384,512) h_n | [512,519) W_e | 519 W_s | pad->528
// 512 threads = 8 waves, ALL compute (no specialization). Wave w owns hidden j in [16w,16w+16):
// frags r=w, z=8+w, i_n=16+w, h_n=24+w -> GRU epilogue wave-local; acc = 8 f32x4 (32 VGPR).
// Heads (frag 32) K-split by (s&7)==w. A staged in 8-step chunks (32 KB) via global_load_lds,
// double-buffered; 2 blocks/CU -> 16 waves/CU (2x round 15's residency).
#define NFR    33
#define NSTEP  53

typedef __attribute__((ext_vector_type(8))) short bf16x8;
typedef __attribute__((ext_vector_type(4))) float f32x4;

#define LD4(p) (*reinterpret_cast<const float4*>(p))
#define MFMA(d, a, b) d = __builtin_amdgcn_mfma_f32_16x16x32_bf16(a, b, d, 0, 0, 0)

// async global->LDS DMA, 16B/lane, dest = wave-uniform base + lane*16
#define GLDS(gp, lp) __builtin_amdgcn_global_load_lds(                              \
        (const __attribute__((address_space(1))) unsigned int*)(gp),                \
        (__attribute__((address_space(3))) unsigned int*)(lp), 16, 0, 0)

static __device__ __forceinline__ ushort f2bf(float v) {
    unsigned u = __float_as_uint(v);
    u = (u + 0x7FFFu + ((u >> 16) & 1u)) >> 16;   // RNE (pack kernel / tail only)
    return (ushort)u;
}

static __device__ __forceinline__ unsigned pk2(float x, float y) {
    unsigned a = __float_as_uint(x) + 0x8000u;
    unsigned b = __float_as_uint(y) + 0x8000u;
    return __builtin_amdgcn_perm(b, a, 0x07060302);   // [a.hi16 | b.hi16]
}

static __device__ __forceinline__ bf16x8 cvt8(float4 a, float4 b) {
    union { unsigned u[4]; bf16x8 v; } r;
    r.u[0] = pk2(a.x, a.y); r.u[1] = pk2(a.z, a.w);
    r.u[2] = pk2(b.x, b.y); r.u[3] = pk2(b.z, b.w);
    return r.v;
}

// logical packed-weight value at (n, k)
static __device__ __forceinline__ float w2_value(int n, int k,
    const float* __restrict__ W_ih, const float* __restrict__ W_hh,
    const float* __restrict__ b_ih, const float* __restrict__ b_hh,
    const float* __restrict__ W_e,  const float* __restrict__ b_e,
    const float* __restrict__ W_s,  const float* __restrict__ b_s)
{
    float v = 0.0f;
    if (n < 256) {
        if (k < 768)                        v = W_ih[(size_t)n * 771 + k];
        else if (k < 896)                   v = W_hh[(size_t)n * 128 + (k - 768)];
        else if (k >= 1664 && k < 1667)     v = W_ih[(size_t)n * 771 + 768 + (k - 1664)];
        else if (k == 1667)                 v = b_ih[n] + b_hh[n];
    } else if (n < 384) {
        if (k < 768)                        v = W_ih[(size_t)n * 771 + k];
        else if (k >= 1664 && k < 1667)     v = W_ih[(size_t)n * 771 + 768 + (k - 1664)];
        else if (k == 1667)                 v = b_ih[n];
    } else if (n < 512) {
        int g = n - 128;
        if (k >= 768 && k < 896)            v = W_hh[(size_t)g * 128 + (k - 768)];
        else if (k == 1667)                 v = b_hh[g];
    } else if (n < 520) {
        int e = n - 512;
        const float* Wr = (e < E_SZ) ? (W_e + (size_t)e * 1667) : W_s;
        if (k < 768)                        v = Wr[k];
        else if (k < 896)                   v = Wr[771 + (k - 768)];
        else if (k < 1664)                  v = Wr[899 + (k - 896)];
        else if (k < 1667)                  v = Wr[768 + (k - 1664)];
        else if (k == 1667)                 v = (e < E_SZ) ? b_e[e] : b_s[0];
    }
    return v;
}

// ---------------- pack W2 frag-major: W2f[(nf*NSTEP + kstep)*64 + lane][8] ----------------
__global__ __launch_bounds__(256) void pack_w2f_kernel(
    const float* __restrict__ W_ih, const float* __restrict__ W_hh,
    const float* __restrict__ b_ih, const float* __restrict__ b_hh,
    const float* __restrict__ W_e,  const float* __restrict__ b_e,
    const float* __restrict__ W_s,  const float* __restrict__ b_s,
    ushort* __restrict__ W2f)
{
    int tid = blockIdx.x * 256 + threadIdx.x;
    if (tid >= NFR * NSTEP * 64) return;
    int lane  = tid & 63;
    int kstep = (tid >> 6) % NSTEP;
    int nf    = tid / (NSTEP * 64);
    int n     = nf * 16 + (lane & 15);
    int kbase = kstep * 32 + (lane >> 4) * 8;
    ushort o[8];
#pragma unroll
    for (int j = 0; j < 8; ++j)
        o[j] = f2bf(w2_value(n, kbase + j, W_ih, W_hh, b_ih, b_hh, W_e, b_e, W_s, b_s));
    *reinterpret_cast<uint4*>(W2f + (size_t)tid * 8) = *reinterpret_cast<const uint4*>(o);
}

// ---------------- winner (last-write-wins) ----------------
__global__ __launch_bounds__(256) void winner_kernel(const int* __restrict__ slot_ids,
                                                     int* __restrict__ winner)
{
    int b = blockIdx.x * 256 + threadIdx.x;
    if (b < B_SZ) atomicMax(&winner[slot_ids[b]], b);
}

static __device__ __forceinline__ bf16x8 ldB(const ushort* __restrict__ W2f, int nf, int ks, int lane) {
    return *reinterpret_cast<const bf16x8*>(W2f + ((size_t)(nf * NSTEP + ks) * 64 + lane) * 8);
}

// LDS A read: 8-step panel, XOR-swizzled (matches pre-swizzled DMA source)
static __device__ __forceinline__ float4 lds_rd(const char* Ab, int st, int row, int h) {
    return *reinterpret_cast<const float4*>(Ab + st * 4096 + row * 128 + ((h ^ (row & 7)) << 4));
}

// h_t chunk (8 steps): frags r, z, i_n; heads at st == W
template<int W>
static __device__ __forceinline__ void chunk_ht8(int c, const char* Ab, int lane,
                                                 const ushort* __restrict__ W2f,
                                                 f32x4* __restrict__ acc, f32x4* __restrict__ hacc)
{
    const int cl = lane & 15, kg = lane >> 4;
#pragma unroll
    for (int st = 0; st < 8; ++st) {
        const int s = c * 8 + st;
        bf16x8 B0 = ldB(W2f, W, s, lane), B1 = ldB(W2f, 8 + W, s, lane), B2 = ldB(W2f, 16 + W, s, lane);
        float4 x0 = lds_rd(Ab, st, cl, 2 * kg), x1 = lds_rd(Ab, st, cl, 2 * kg + 1);
        bf16x8 a0 = cvt8(x0, x1);
        MFMA(acc[0], a0, B0); MFMA(acc[1], a0, B1); MFMA(acc[2], a0, B2);
        float4 y0 = lds_rd(Ab, st, 16 + cl, 2 * kg), y1 = lds_rd(Ab, st, 16 + cl, 2 * kg + 1);
        bf16x8 a1 = cvt8(y0, y1);
        MFMA(acc[4], a1, B0); MFMA(acc[5], a1, B1); MFMA(acc[6], a1, B2);
        if (st == W) {
            bf16x8 Bh = ldB(W2f, 32, s, lane);
            MFMA(hacc[0], a0, Bh); MFMA(hacc[1], a1, Bh);
        }
    }
}

// chunk 3: slots 0-3 = s_t steps 24-27 (r, z, h_n; heads for W<4 at t==W);
//          slots 4-7 = ctx steps 28-31 (heads only, wave W>=4 handles slot W)
template<int W>
static __device__ __forceinline__ void chunk_c3(const char* Ab, int lane,
                                                const ushort* __restrict__ W2f,
                                                f32x4* __restrict__ acc, f32x4* __restrict__ hacc)
{
    const int cl = lane & 15, kg = lane >> 4;
#pragma unroll
    for (int t = 0; t < 4; ++t) {
        const int s = 24 + t;
        bf16x8 B0 = ldB(W2f, W, s, lane), B1 = ldB(W2f, 8 + W, s, lane), B2 = ldB(W2f, 24 + W, s, lane);
        float4 x0 = lds_rd(Ab, t, cl, 2 * kg), x1 = lds_rd(Ab, t, cl, 2 * kg + 1);
        bf16x8 a0 = cvt8(x0, x1);
        MFMA(acc[0], a0, B0); MFMA(acc[1], a0, B1); MFMA(acc[3], a0, B2);
        float4 y0 = lds_rd(Ab, t, 16 + cl, 2 * kg), y1 = lds_rd(Ab, t, 16 + cl, 2 * kg + 1);
        bf16x8 a1 = cvt8(y0, y1);
        MFMA(acc[4], a1, B0); MFMA(acc[5], a1, B1); MFMA(acc[7], a1, B2);
        if constexpr (W < 4) {
            if (t == W) {
                bf16x8 Bh = ldB(W2f, 32, s, lane);
                MFMA(hacc[0], a0, Bh); MFMA(hacc[1], a1, Bh);
            }
        }
    }
    if constexpr (W >= 4) {          // ctx step s = 24+W (28..31), lds slot W
        bf16x8 Bh = ldB(W2f, 32, 24 + W, lane);
        float4 x0 = lds_rd(Ab, W, cl, 2 * kg), x1 = lds_rd(Ab, W, cl, 2 * kg + 1);
        MFMA(hacc[0], cvt8(x0, x1), Bh);
        float4 y0 = lds_rd(Ab, W, 16 + cl, 2 * kg), y1 = lds_rd(Ab, W, 16 + cl, 2 * kg + 1);
        MFMA(hacc[1], cvt8(y0, y1), Bh);
    }
}

// ctx chunk (8 steps): wave W handles slot W, step s = c*8 + W
template<int W>
static __device__ __forceinline__ void ctx_chunk8(int c, const char* Ab, int lane,
                                                  const ushort* __restrict__ W2f,
                                                  f32x4* __restrict__ hacc)
{
    const int cl = lane & 15, kg = lane >> 4;
    const int s = c * 8 + W;
    bf16x8 Bh = ldB(W2f, 32, s, lane);
    float4 x0 = lds_rd(Ab, W, cl, 2 * kg), x1 = lds_rd(Ab, W, cl, 2 * kg + 1);
    MFMA(hacc[0], cvt8(x0, x1), Bh);
    float4 y0 = lds_rd(Ab, W, 16 + cl, 2 * kg), y1 = lds_rd(Ab, W, 16 + cl, 2 * kg + 1);
    MFMA(hacc[1], cvt8(y0, y1), Bh);
}

// ctx chunk 6 (4 steps 48-51): waves 0-3 only
template<int W>
static __device__ __forceinline__ void ctx_chunk4(const char* Ab, int lane,
                                                  const ushort* __restrict__ W2f,
                                                  f32x4* __restrict__ hacc)
{
    if constexpr (W < 4) {
        const int cl = lane & 15, kg = lane >> 4;
        bf16x8 Bh = ldB(W2f, 32, 48 + W, lane);
        float4 x0 = lds_rd(Ab, W, cl, 2 * kg), x1 = lds_rd(Ab, W, cl, 2 * kg + 1);
        MFMA(hacc[0], cvt8(x0, x1), Bh);
        float4 y0 = lds_rd(Ab, W, 16 + cl, 2 * kg), y1 = lds_rd(Ab, W, 16 + cl, 2 * kg + 1);
        MFMA(hacc[1], cvt8(y0, y1), Bh);
    }
}

// tail step 52 + wave-local GRU epilogue
template<int W>
static __device__ __forceinline__ void tail_and_gru(
    const float* __restrict__ sent, const float* __restrict__ memory,
    const int* __restrict__ slot_ids, const int* __restrict__ winner,
    int row0, int lane, const ushort* __restrict__ W2f,
    f32x4* __restrict__ acc, f32x4* __restrict__ hacc, float* __restrict__ out_mem)
{
    const int cl = lane & 15, kg = lane >> 4;
    // tail (k=1664..1695): sent(3) + bias-one + zeros
    {
        const int rA0 = row0 + cl, rA1 = rA0 + 16;
        bf16x8 a0, a1;
#pragma unroll
        for (int jj = 0; jj < 8; ++jj) {
            int kk = kg * 8 + jj;
            float v0 = 0.f, v1 = 0.f;
            if (kk < 3)       { v0 = sent[(size_t)rA0 * 3 + kk]; v1 = sent[(size_t)rA1 * 3 + kk]; }
            else if (kk == 3) { v0 = 1.f; v1 = 1.f; }
            a0[jj] = (short)f2bf(v0); a1[jj] = (short)f2bf(v1);
        }
        bf16x8 T0 = ldB(W2f, W, 52, lane),      T1 = ldB(W2f, 8 + W, 52, lane);
        bf16x8 T2 = ldB(W2f, 16 + W, 52, lane), T3 = ldB(W2f, 24 + W, 52, lane);
        MFMA(acc[0], a0, T0); MFMA(acc[1], a0, T1);
        MFMA(acc[2], a0, T2); MFMA(acc[3], a0, T3);
        MFMA(acc[4], a1, T0); MFMA(acc[5], a1, T1);
        MFMA(acc[6], a1, T2); MFMA(acc[7], a1, T3);
        if constexpr (W == 4) {   // step 52: (52&7)==4
            bf16x8 Bh = ldB(W2f, 32, 52, lane);
            MFMA(hacc[0], a0, Bh); MFMA(hacc[1], a1, Bh);
        }
    }
    // wave-local GRU + winner scatter for hidden j = 16W + cl
    const int j = 16 * W + cl;
#pragma unroll
    for (int rg = 0; rg < 2; ++rg) {
#pragma unroll
        for (int rr = 0; rr < 4; ++rr) {
            const int row  = row0 + rg * 16 + kg * 4 + rr;
            const int slot = slot_ids[row];
            const bool win = (winner[slot] == row);
            float rgate = acc[rg * 4 + 0][rr];
            float zg    = acc[rg * 4 + 1][rr];
            float inn   = acc[rg * 4 + 2][rr];
            float hnn   = acc[rg * 4 + 3][rr];
            rgate = 1.0f / (1.0f + __expf(-rgate));
            zg    = 1.0f / (1.0f + __expf(-zg));
            float nn = tanhf(inn + rgate * hnn);
            float h  = memory[(size_t)slot * H_SZ + j];   // exact f32 pre-update state
            float sn = (1.0f - zg) * nn + zg * h;
            if (win) out_mem[(size_t)slot * H_SZ + j] = sn;
        }
    }
}

// ---------------- fused kernel: 8 waves, all compute ----------------
__global__ __launch_bounds__(512, 4) void fused_kernel(
    const float* __restrict__ h_t,   const float* __restrict__ h_ctx,
    const float* __restrict__ sent,  const int* __restrict__ slot_ids,
    const float* __restrict__ memory,const ushort* __restrict__ W2f,
    const int* __restrict__ winner,
    float* __restrict__ out_emo, float* __restrict__ out_shift, float* __restrict__ out_mem)
{
    __shared__ alignas(16) char  A_st[2][8 * 4096];   // 64 KB
    __shared__ alignas(16) f32x4 redh[8 * 64];        // 8 KB heads partials (two-phase reuse)

    const int tid  = threadIdx.x;
    const int wave = tid >> 6;
    const int lane = tid & 63;
    const int row0 = blockIdx.x * 32;

    // staging identity: 512 threads cover 2 steps per round; shalf = step parity
    const int st8   = tid & 255;
    const int srow  = st8 >> 3;                 // 0..31
    const int scg   = (st8 & 7) ^ (srow & 7);   // pre-swizzled source chunk
    const int shalf = tid >> 8;                 // 0/1
    const int sslot = slot_ids[row0 + srow];
    const int wb    = (wave & 3) * 1024;        // wave panel base within a step

    f32x4 acc[8], hacc[2];
    {
        f32x4 z = {0.f, 0.f, 0.f, 0.f};
#pragma unroll
        for (int i = 0; i < 8; ++i) acc[i] = z;
        hacc[0] = z; hacc[1] = z;
    }

#define STAGE_HT8(BUF, S0) do { _Pragma("unroll")                                         \
    for (int q = 0; q < 4; ++q) { int stp = 2 * q + shalf;                                \
        GLDS(h_t + (size_t)(row0 + srow) * D_SZ + ((S0) + stp) * 32 + scg * 4,            \
             &A_st[BUF][stp * 4096 + wb]); } } while (0)

#define STAGE_MEMCTX(BUF) do { _Pragma("unroll")                                          \
    for (int q = 0; q < 4; ++q) { int stp = 2 * q + shalf;                                \
        if (stp < 4) GLDS(memory + (size_t)sslot * H_SZ + stp * 32 + scg * 4,             \
                          &A_st[BUF][stp * 4096 + wb]);                                   \
        else GLDS(h_ctx + (size_t)(row0 + srow) * D_SZ + (stp - 4) * 32 + scg * 4,        \
                  &A_st[BUF][stp * 4096 + wb]); } } while (0)

#define STAGE_CTX8(BUF, X0) do { _Pragma("unroll")                                        \
    for (int q = 0; q < 4; ++q) { int stp = 2 * q + shalf;                                \
        GLDS(h_ctx + (size_t)(row0 + srow) * D_SZ + ((X0) + stp) * 32 + scg * 4,          \
             &A_st[BUF][stp * 4096 + wb]); } } while (0)

#define STAGE_CTX4(BUF, X0) do { _Pragma("unroll")                                        \
    for (int q = 0; q < 2; ++q) { int stp = 2 * q + shalf;                                \
        GLDS(h_ctx + (size_t)(row0 + srow) * D_SZ + ((X0) + stp) * 32 + scg * 4,          \
             &A_st[BUF][stp * 4096 + wb]); } } while (0)

#define COPYSL(I0, N) do {                                                                \
    for (int k = 0; k < (N); ++k) {                                                       \
        int idx  = ((I0) + k) * 512 + tid;                                                \
        int rr   = idx >> 5;                                                              \
        int c4   = (idx & 31) * 4;                                                        \
        int slot = blockIdx.x * 128 + rr;                                                 \
        if (winner[slot] < 0) {                                                           \
            float4 v = LD4(memory + (size_t)slot * H_SZ + c4);                            \
            *reinterpret_cast<float4*>(out_mem + (size_t)slot * H_SZ + c4) = v;           \
        } } } while (0)

#define BYWAVE(...) do { switch (wave) {                                                  \
    case 0: { constexpr int W = 0; __VA_ARGS__; } break;                                  \
    case 1: { constexpr int W = 1; __VA_ARGS__; } break;                                  \
    case 2: { constexpr int W = 2; __VA_ARGS__; } break;                                  \
    case 3: { constexpr int W = 3; __VA_ARGS__; } break;                                  \
    case 4: { constexpr int W = 4; __VA_ARGS__; } break;                                  \
    case 5: { constexpr int W = 5; __VA_ARGS__; } break;                                  \
    case 6: { constexpr int W = 6; __VA_ARGS__; } break;                                  \
    default:{ constexpr int W = 7; __VA_ARGS__; } break; } } while (0)

    // prologue: stage chunk 0 (h_t steps 0-7)
    STAGE_HT8(0, 0);
    __syncthreads();

    // iter 0: compute c0 (buf0); copy 2; stage c1 (h_t 8-15 -> buf1)
    BYWAVE(chunk_ht8<W>(0, A_st[0], lane, W2f, acc, hacc));
    COPYSL(0, 2);
    STAGE_HT8(1, 8);
    __syncthreads();

    // iter 1: c1 (buf1); stage c2 (h_t 16-23 -> buf0)
    BYWAVE(chunk_ht8<W>(1, A_st[1], lane, W2f, acc, hacc));
    COPYSL(2, 1);
    STAGE_HT8(0, 16);
    __syncthreads();

    // iter 2: c2 (buf0); stage c3 (s_t + ctx 28-31 -> buf1)
    BYWAVE(chunk_ht8<W>(2, A_st[0], lane, W2f, acc, hacc));
    COPYSL(3, 1);
    STAGE_MEMCTX(1);
    __syncthreads();

    // iter 3: c3 (buf1); stage c4 (ctx 32-39 -> buf0)
    BYWAVE(chunk_c3<W>(A_st[1], lane, W2f, acc, hacc));
    COPYSL(4, 1);
    STAGE_CTX8(0, 4);
    __syncthreads();

    // iter 4: c4 (buf0); stage c5 (ctx 40-47 -> buf1)
    BYWAVE(ctx_chunk8<W>(4, A_st[0], lane, W2f, hacc));
    COPYSL(5, 1);
    STAGE_CTX8(1, 12);
    __syncthreads();

    // iter 5: c5 (buf1); stage c6 (ctx 48-51 -> buf0)
    BYWAVE(ctx_chunk8<W>(5, A_st[1], lane, W2f, hacc));
    COPYSL(6, 1);
    STAGE_CTX4(0, 20);
    __syncthreads();

    // iter 6: c6 (buf0) + tail + wave-local GRU
    BYWAVE((ctx_chunk4<W>(A_st[0], lane, W2f, hacc),
            tail_and_gru<W>(sent, memory, slot_ids, winner, row0, lane, W2f,
                            acc, hacc, out_mem)));
    COPYSL(7, 1);

    // heads outputs: two-phase LDS reduction over 8 waves
#pragma unroll
    for (int rg = 0; rg < 2; ++rg) {
        __syncthreads();
        redh[wave * 64 + lane] = hacc[rg];
        __syncthreads();
        if (tid < 64) {
            f32x4 hv = redh[tid];
#pragma unroll
            for (int w = 1; w < 8; ++w) hv += redh[w * 64 + tid];
            const int col  = tid & 15;
            const int rowb = row0 + rg * 16 + (tid >> 4) * 4;
#pragma unroll
            for (int rr = 0; rr < 4; ++rr) {
                const int row = rowb + rr;
                if (col < E_SZ)       out_emo[(size_t)row * E_SZ + col] = hv[rr];
                else if (col == E_SZ) out_shift[row] = hv[rr];
            }
        }
    }
#undef STAGE_HT8
#undef STAGE_MEMCTX
#undef STAGE_CTX8
#undef STAGE_CTX4
#undef COPYSL
#undef BYWAVE
}

// ---------------- launch ----------------
extern "C" void kernel_launch(void* const* d_in, const int* in_sizes, int n_in,
                              void* d_out, int out_size, void* d_ws, size_t ws_size,
                              hipStream_t stream)
{
    const float* h_t     = (const float*)d_in[0];
    const float* h_ctx   = (const float*)d_in[1];
    const float* sent    = (const float*)d_in[2];
    const int*   slot_ids= (const int*)  d_in[3];
    const float* memory  = (const float*)d_in[4];
    const float* W_ih    = (const float*)d_in[5];
    const float* W_hh    = (const float*)d_in[6];
    const float* b_ih    = (const float*)d_in[7];
    const float* b_hh    = (const float*)d_in[8];
    const float* W_e     = (const float*)d_in[9];
    const float* b_e     = (const float*)d_in[10];
    const float* W_s     = (const float*)d_in[11];
    const float* b_s     = (const float*)d_in[12];

    float* out       = (float*)d_out;
    float* out_emo   = out;                                    // [B,7]
    float* out_shift = out + (size_t)B_SZ * E_SZ;              // [B]
    float* out_mem   = out + (size_t)B_SZ * E_SZ + B_SZ;       // [S,H]

    int*    winner = (int*)d_ws;                               // S ints
    ushort* W2f    = (ushort*)((char*)d_ws + (size_t)S_SZ * sizeof(int));

    hipMemsetAsync(winner, 0xFF, (size_t)S_SZ * sizeof(int), stream);   // -1

    pack_w2f_kernel<<<(NFR * NSTEP * 64 + 255) / 256, 256, 0, stream>>>(
        W_ih, W_hh, b_ih, b_hh, W_e, b_e, W_s, b_s, W2f);
    winner_kernel<<<B_SZ / 256, 256, 0, stream>>>(slot_ids, winner);
    fused_kernel<<<B_SZ / 32, 512, 0, stream>>>(
        h_t, h_ctx, sent, slot_ids, memory, W2f, winner, out_emo, out_shift, out_mem);
}

// Round 17
// 75.276 us; speedup vs baseline: 1.7746x; 1.0251x over previous
//
#include <hip/hip_runtime.h>
#include <hip/hip_bf16.h>

// Problem constants
#define B_SZ   16384
#define D_SZ   768
#define H_SZ   128
#define S_SZ   65536
#define E_SZ   7

// K layout: [0,768) h_t | [768,896) s_t | [896,1664) h_ctx | 1664..1666 sent | 1667 bias | pad->1696
// N layout: [0,256) r,z summed | [256,384) i_n | [384,512) h_n | [512,519) W_e | 519 W_s | pad->528
// M=16 per block, 1024 blocks, 512 threads = 8 waves ALL compute. Wave w owns hidden j in
// [16w,16w+16): frags r=w, z=8+w, i_n=16+w, h_n=24+w -> wave-local GRU; acc = 4 f32x4 (16 VGPR).
// Heads (frag 32) K-split by (s mod 8)==w. A staged in 8-step chunks (16 KB) via global_load_lds,
// double-buffered; LDS 40 KB -> 4 blocks/CU -> 32 waves/CU (2x round 16).
#define NFR    33
#define NSTEP  53

typedef __attribute__((ext_vector_type(8))) short bf16x8;
typedef __attribute__((ext_vector_type(4))) float f32x4;

#define LD4(p) (*reinterpret_cast<const float4*>(p))
#define MFMA(d, a, b) d = __builtin_amdgcn_mfma_f32_16x16x32_bf16(a, b, d, 0, 0, 0)

// async global->LDS DMA, 16B/lane, dest = wave-uniform base + lane*16
#define GLDS(gp, lp) __builtin_amdgcn_global_load_lds(                              \
        (const __attribute__((address_space(1))) unsigned int*)(gp),                \
        (__attribute__((address_space(3))) unsigned int*)(lp), 16, 0, 0)

static __device__ __forceinline__ ushort f2bf(float v) {
    unsigned u = __float_as_uint(v);
    u = (u + 0x7FFFu + ((u >> 16) & 1u)) >> 16;   // RNE (pack kernel / tail only)
    return (ushort)u;
}

static __device__ __forceinline__ unsigned pk2(float x, float y) {
    unsigned a = __float_as_uint(x) + 0x8000u;
    unsigned b = __float_as_uint(y) + 0x8000u;
    return __builtin_amdgcn_perm(b, a, 0x07060302);   // [a.hi16 | b.hi16]
}

static __device__ __forceinline__ bf16x8 cvt8(float4 a, float4 b) {
    union { unsigned u[4]; bf16x8 v; } r;
    r.u[0] = pk2(a.x, a.y); r.u[1] = pk2(a.z, a.w);
    r.u[2] = pk2(b.x, b.y); r.u[3] = pk2(b.z, b.w);
    return r.v;
}

// logical packed-weight value at (n, k)
static __device__ __forceinline__ float w2_value(int n, int k,
    const float* __restrict__ W_ih, const float* __restrict__ W_hh,
    const float* __restrict__ b_ih, const float* __restrict__ b_hh,
    const float* __restrict__ W_e,  const float* __restrict__ b_e,
    const float* __restrict__ W_s,  const float* __restrict__ b_s)
{
    float v = 0.0f;
    if (n < 256) {
        if (k < 768)                        v = W_ih[(size_t)n * 771 + k];
        else if (k < 896)                   v = W_hh[(size_t)n * 128 + (k - 768)];
        else if (k >= 1664 && k < 1667)     v = W_ih[(size_t)n * 771 + 768 + (k - 1664)];
        else if (k == 1667)                 v = b_ih[n] + b_hh[n];
    } else if (n < 384) {
        if (k < 768)                        v = W_ih[(size_t)n * 771 + k];
        else if (k >= 1664 && k < 1667)     v = W_ih[(size_t)n * 771 + 768 + (k - 1664)];
        else if (k == 1667)                 v = b_ih[n];
    } else if (n < 512) {
        int g = n - 128;
        if (k >= 768 && k < 896)            v = W_hh[(size_t)g * 128 + (k - 768)];
        else if (k == 1667)                 v = b_hh[g];
    } else if (n < 520) {
        int e = n - 512;
        const float* Wr = (e < E_SZ) ? (W_e + (size_t)e * 1667) : W_s;
        if (k < 768)                        v = Wr[k];
        else if (k < 896)                   v = Wr[771 + (k - 768)];
        else if (k < 1664)                  v = Wr[899 + (k - 896)];
        else if (k < 1667)                  v = Wr[768 + (k - 1664)];
        else if (k == 1667)                 v = (e < E_SZ) ? b_e[e] : b_s[0];
    }
    return v;
}

// ---------------- pack W2 frag-major: W2f[(nf*NSTEP + kstep)*64 + lane][8] ----------------
__global__ __launch_bounds__(256) void pack_w2f_kernel(
    const float* __restrict__ W_ih, const float* __restrict__ W_hh,
    const float* __restrict__ b_ih, const float* __restrict__ b_hh,
    const float* __restrict__ W_e,  const float* __restrict__ b_e,
    const float* __restrict__ W_s,  const float* __restrict__ b_s,
    ushort* __restrict__ W2f)
{
    int tid = blockIdx.x * 256 + threadIdx.x;
    if (tid >= NFR * NSTEP * 64) return;
    int lane  = tid & 63;
    int kstep = (tid >> 6) % NSTEP;
    int nf    = tid / (NSTEP * 64);
    int n     = nf * 16 + (lane & 15);
    int kbase = kstep * 32 + (lane >> 4) * 8;
    ushort o[8];
#pragma unroll
    for (int j = 0; j < 8; ++j)
        o[j] = f2bf(w2_value(n, kbase + j, W_ih, W_hh, b_ih, b_hh, W_e, b_e, W_s, b_s));
    *reinterpret_cast<uint4*>(W2f + (size_t)tid * 8) = *reinterpret_cast<const uint4*>(o);
}

// ---------------- winner (last-write-wins) ----------------
__global__ __launch_bounds__(256) void winner_kernel(const int* __restrict__ slot_ids,
                                                     int* __restrict__ winner)
{
    int b = blockIdx.x * 256 + threadIdx.x;
    if (b < B_SZ) atomicMax(&winner[slot_ids[b]], b);
}

static __device__ __forceinline__ bf16x8 ldB(const ushort* __restrict__ W2f, int nf, int ks, int lane) {
    return *reinterpret_cast<const bf16x8*>(W2f + ((size_t)(nf * NSTEP + ks) * 64 + lane) * 8);
}

// LDS A read: 8-step panel of [16 rows][128 B], XOR-swizzled (matches pre-swizzled DMA source)
static __device__ __forceinline__ float4 lds_rd(const char* Ab, int st, int row, int h) {
    return *reinterpret_cast<const float4*>(Ab + st * 2048 + row * 128 + ((h ^ (row & 7)) << 4));
}

// h_t chunk (8 steps): frags r=W, z=8+W, i_n=16+W; heads at st == W
template<int W>
static __device__ __forceinline__ void chunk_ht8(int c, const char* Ab, int lane,
                                                 const ushort* __restrict__ W2f,
                                                 f32x4* __restrict__ acc, f32x4* __restrict__ hacc)
{
    const int cl = lane & 15, kg = lane >> 4;
#pragma unroll
    for (int st = 0; st < 8; ++st) {
        const int s = c * 8 + st;
        bf16x8 B0 = ldB(W2f, W, s, lane), B1 = ldB(W2f, 8 + W, s, lane), B2 = ldB(W2f, 16 + W, s, lane);
        float4 x0 = lds_rd(Ab, st, cl, 2 * kg), x1 = lds_rd(Ab, st, cl, 2 * kg + 1);
        bf16x8 a0 = cvt8(x0, x1);
        MFMA(acc[0], a0, B0); MFMA(acc[1], a0, B1); MFMA(acc[2], a0, B2);
        if (st == W) {
            bf16x8 Bh = ldB(W2f, 32, s, lane);
            MFMA(hacc[0], a0, Bh);
        }
    }
}

// chunk 3: slots 0-3 = s_t steps 24-27 (r, z, h_n; heads for W<4 at t==W);
//          slots 4-7 = ctx steps 28-31 (heads only; wave W>=4 handles slot W)
template<int W>
static __device__ __forceinline__ void chunk_c3(const char* Ab, int lane,
                                                const ushort* __restrict__ W2f,
                                                f32x4* __restrict__ acc, f32x4* __restrict__ hacc)
{
    const int cl = lane & 15, kg = lane >> 4;
#pragma unroll
    for (int t = 0; t < 4; ++t) {
        const int s = 24 + t;
        bf16x8 B0 = ldB(W2f, W, s, lane), B1 = ldB(W2f, 8 + W, s, lane), B2 = ldB(W2f, 24 + W, s, lane);
        float4 x0 = lds_rd(Ab, t, cl, 2 * kg), x1 = lds_rd(Ab, t, cl, 2 * kg + 1);
        bf16x8 a0 = cvt8(x0, x1);
        MFMA(acc[0], a0, B0); MFMA(acc[1], a0, B1); MFMA(acc[3], a0, B2);
        if constexpr (W < 4) {
            if (t == W) {
                bf16x8 Bh = ldB(W2f, 32, s, lane);
                MFMA(hacc[0], a0, Bh);
            }
        }
    }
    if constexpr (W >= 4) {          // ctx step s = 24+W (28..31), lds slot W
        bf16x8 Bh = ldB(W2f, 32, 24 + W, lane);
        float4 x0 = lds_rd(Ab, W, cl, 2 * kg), x1 = lds_rd(Ab, W, cl, 2 * kg + 1);
        MFMA(hacc[0], cvt8(x0, x1), Bh);
    }
}

// ctx chunk (8 steps): wave W handles lds slot W, step s = sbase + W
template<int W>
static __device__ __forceinline__ void ctx_chunk8(int sbase, const char* Ab, int lane,
                                                  const ushort* __restrict__ W2f,
                                                  f32x4* __restrict__ hacc)
{
    const int cl = lane & 15, kg = lane >> 4;
    bf16x8 Bh = ldB(W2f, 32, sbase + W, lane);
    float4 x0 = lds_rd(Ab, W, cl, 2 * kg), x1 = lds_rd(Ab, W, cl, 2 * kg + 1);
    MFMA(hacc[0], cvt8(x0, x1), Bh);
}

// ctx chunk 6 (4 steps 48-51): waves 0-3 only
template<int W>
static __device__ __forceinline__ void ctx_chunk4(const char* Ab, int lane,
                                                  const ushort* __restrict__ W2f,
                                                  f32x4* __restrict__ hacc)
{
    if constexpr (W < 4) {
        const int cl = lane & 15, kg = lane >> 4;
        bf16x8 Bh = ldB(W2f, 32, 48 + W, lane);
        float4 x0 = lds_rd(Ab, W, cl, 2 * kg), x1 = lds_rd(Ab, W, cl, 2 * kg + 1);
        MFMA(hacc[0], cvt8(x0, x1), Bh);
    }
}

// tail step 52 + wave-local GRU epilogue
template<int W>
static __device__ __forceinline__ void tail_and_gru(
    const float* __restrict__ sent, const float* __restrict__ memory,
    const int* __restrict__ slot_ids, const int* __restrict__ winner,
    int row0, int lane, const ushort* __restrict__ W2f,
    f32x4* __restrict__ acc, f32x4* __restrict__ hacc, float* __restrict__ out_mem)
{
    const int cl = lane & 15, kg = lane >> 4;
    // tail (k=1664..1695): sent(3) + bias-one + zeros
    {
        const int rA0 = row0 + cl;
        bf16x8 a0;
#pragma unroll
        for (int jj = 0; jj < 8; ++jj) {
            int kk = kg * 8 + jj;
            float v0 = 0.f;
            if (kk < 3)       v0 = sent[(size_t)rA0 * 3 + kk];
            else if (kk == 3) v0 = 1.f;
            a0[jj] = (short)f2bf(v0);
        }
        bf16x8 T0 = ldB(W2f, W, 52, lane),      T1 = ldB(W2f, 8 + W, 52, lane);
        bf16x8 T2 = ldB(W2f, 16 + W, 52, lane), T3 = ldB(W2f, 24 + W, 52, lane);
        MFMA(acc[0], a0, T0); MFMA(acc[1], a0, T1);
        MFMA(acc[2], a0, T2); MFMA(acc[3], a0, T3);
        if constexpr (W == 4) {   // step 52: (52&7)==4
            bf16x8 Bh = ldB(W2f, 32, 52, lane);
            MFMA(hacc[0], a0, Bh);
        }
    }
    // wave-local GRU + winner scatter for hidden j = 16W + cl
    const int j = 16 * W + cl;
#pragma unroll
    for (int rr = 0; rr < 4; ++rr) {
        const int row  = row0 + kg * 4 + rr;
        const int slot = slot_ids[row];
        const bool win = (winner[slot] == row);
        float rgate = acc[0][rr];
        float zg    = acc[1][rr];
        float inn   = acc[2][rr];
        float hnn   = acc[3][rr];
        rgate = 1.0f / (1.0f + __expf(-rgate));
        zg    = 1.0f / (1.0f + __expf(-zg));
        float nn = tanhf(inn + rgate * hnn);
        float h  = memory[(size_t)slot * H_SZ + j];   // exact f32 pre-update state
        float sn = (1.0f - zg) * nn + zg * h;
        if (win) out_mem[(size_t)slot * H_SZ + j] = sn;
    }
}

// ---------------- fused kernel: M=16, 8 waves all-compute, 4 blocks/CU ----------------
__global__ __launch_bounds__(512, 8) void fused_kernel(
    const float* __restrict__ h_t,   const float* __restrict__ h_ctx,
    const float* __restrict__ sent,  const int* __restrict__ slot_ids,
    const float* __restrict__ memory,const ushort* __restrict__ W2f,
    const int* __restrict__ winner,
    float* __restrict__ out_emo, float* __restrict__ out_shift, float* __restrict__ out_mem)
{
    __shared__ alignas(16) char  A_st[2][8 * 2048];   // 32 KB: 2 bufs x 8 steps x [16 rows][128 B]
    __shared__ alignas(16) f32x4 redh[8 * 64];        // 8 KB heads partials

    const int tid  = threadIdx.x;
    const int wave = tid >> 6;
    const int lane = tid & 63;
    const int row0 = blockIdx.x * 16;

    // staging identity: unit = round*512 + tid covers (st = round*4 + (wave>>1),
    // w128 = (wave&1)*64 + lane); row = w128>>3 (0..15), cg pre-swizzled.
    const int srow  = (tid & 127) >> 3;
    const int scg   = (lane & 7) ^ (srow & 7);
    const int sbh   = (wave & 1) * 1024;        // half-panel base within a step
    const int sst0  = wave >> 1;                // round-0 step (0..3); round-1 adds 4
    const int sslot = slot_ids[row0 + srow];

    f32x4 acc[4], hacc[1];
    {
        f32x4 z = {0.f, 0.f, 0.f, 0.f};
#pragma unroll
        for (int i = 0; i < 4; ++i) acc[i] = z;
        hacc[0] = z;
    }

#define STAGE_HT8(BUF, S0) do { _Pragma("unroll")                                         \
    for (int rd = 0; rd < 2; ++rd) { int stp = rd * 4 + sst0;                             \
        GLDS(h_t + (size_t)(row0 + srow) * D_SZ + ((S0) + stp) * 32 + scg * 4,            \
             &A_st[BUF][stp * 2048 + sbh]); } } while (0)

#define STAGE_MEMCTX(BUF) do { _Pragma("unroll")                                          \
    for (int rd = 0; rd < 2; ++rd) { int stp = rd * 4 + sst0;                             \
        if (stp < 4) GLDS(memory + (size_t)sslot * H_SZ + stp * 32 + scg * 4,             \
                          &A_st[BUF][stp * 2048 + sbh]);                                  \
        else GLDS(h_ctx + (size_t)(row0 + srow) * D_SZ + (stp - 4) * 32 + scg * 4,        \
                  &A_st[BUF][stp * 2048 + sbh]); } } while (0)

#define STAGE_CTX8(BUF, X0) do { _Pragma("unroll")                                        \
    for (int rd = 0; rd < 2; ++rd) { int stp = rd * 4 + sst0;                             \
        GLDS(h_ctx + (size_t)(row0 + srow) * D_SZ + ((X0) + stp) * 32 + scg * 4,          \
             &A_st[BUF][stp * 2048 + sbh]); } } while (0)

#define STAGE_CTX4(BUF, X0) do { int stp = sst0;                                          \
        GLDS(h_ctx + (size_t)(row0 + srow) * D_SZ + ((X0) + stp) * 32 + scg * 4,          \
             &A_st[BUF][stp * 2048 + sbh]); } while (0)

#define COPYSL(I0, N) do {                                                                \
    for (int k = 0; k < (N); ++k) {                                                       \
        int idx  = ((I0) + k) * 512 + tid;       /* 0..2047 over 4 rounds */              \
        int rr   = idx >> 5;                     /* slot row 0..63 */                     \
        int c4   = (idx & 31) * 4;                                                        \
        int slot = blockIdx.x * 64 + rr;                                                  \
        if (winner[slot] < 0) {                                                           \
            float4 v = LD4(memory + (size_t)slot * H_SZ + c4);                            \
            *reinterpret_cast<float4*>(out_mem + (size_t)slot * H_SZ + c4) = v;           \
        } } } while (0)

#define BYWAVE(...) do { switch (wave) {                                                  \
    case 0: { constexpr int W = 0; __VA_ARGS__; } break;                                  \
    case 1: { constexpr int W = 1; __VA_ARGS__; } break;                                  \
    case 2: { constexpr int W = 2; __VA_ARGS__; } break;                                  \
    case 3: { constexpr int W = 3; __VA_ARGS__; } break;                                  \
    case 4: { constexpr int W = 4; __VA_ARGS__; } break;                                  \
    case 5: { constexpr int W = 5; __VA_ARGS__; } break;                                  \
    case 6: { constexpr int W = 6; __VA_ARGS__; } break;                                  \
    default:{ constexpr int W = 7; __VA_ARGS__; } break; } } while (0)

    // prologue: stage chunk 0 (h_t steps 0-7)
    STAGE_HT8(0, 0);
    __syncthreads();

    // iter 0: compute c0 (buf0); stage c1 (h_t 8-15 -> buf1)
    BYWAVE(chunk_ht8<W>(0, A_st[0], lane, W2f, acc, hacc));
    COPYSL(0, 1);
    STAGE_HT8(1, 8);
    __syncthreads();

    // iter 1: c1 (buf1); stage c2 (h_t 16-23 -> buf0)
    BYWAVE(chunk_ht8<W>(1, A_st[1], lane, W2f, acc, hacc));
    COPYSL(1, 1);
    STAGE_HT8(0, 16);
    __syncthreads();

    // iter 2: c2 (buf0); stage c3 (s_t + ctx 28-31 -> buf1)
    BYWAVE(chunk_ht8<W>(2, A_st[0], lane, W2f, acc, hacc));
    COPYSL(2, 1);
    STAGE_MEMCTX(1);
    __syncthreads();

    // iter 3: c3 (buf1); stage c4 (ctx 32-39 -> buf0)
    BYWAVE(chunk_c3<W>(A_st[1], lane, W2f, acc, hacc));
    COPYSL(3, 1);
    STAGE_CTX8(0, 4);
    __syncthreads();

    // iter 4: c4 (buf0, s=32-39); stage c5 (ctx 40-47 -> buf1)
    BYWAVE(ctx_chunk8<W>(32, A_st[0], lane, W2f, hacc));
    STAGE_CTX8(1, 12);
    __syncthreads();

    // iter 5: c5 (buf1, s=40-47); stage c6 (ctx 48-51 -> buf0)
    BYWAVE(ctx_chunk8<W>(40, A_st[1], lane, W2f, hacc));
    STAGE_CTX4(0, 20);
    __syncthreads();

    // iter 6: c6 (buf0, s=48-51) + tail + wave-local GRU
    BYWAVE((ctx_chunk4<W>(A_st[0], lane, W2f, hacc),
            tail_and_gru<W>(sent, memory, slot_ids, winner, row0, lane, W2f,
                            acc, hacc, out_mem)));

    // heads outputs: LDS reduction over 8 waves
    __syncthreads();
    redh[wave * 64 + lane] = hacc[0];
    __syncthreads();
    if (tid < 64) {
        f32x4 hv = redh[tid];
#pragma unroll
        for (int w = 1; w < 8; ++w) hv += redh[w * 64 + tid];
        const int col  = tid & 15;
        const int rowb = row0 + (tid >> 4) * 4;
#pragma unroll
        for (int rr = 0; rr < 4; ++rr) {
            const int row = rowb + rr;
            if (col < E_SZ)       out_emo[(size_t)row * E_SZ + col] = hv[rr];
            else if (col == E_SZ) out_shift[row] = hv[rr];
        }
    }
#undef STAGE_HT8
#undef STAGE_MEMCTX
#undef STAGE_CTX8
#undef STAGE_CTX4
#undef COPYSL
#undef BYWAVE
}

// ---------------- launch ----------------
extern "C" void kernel_launch(void* const* d_in, const int* in_sizes, int n_in,
                              void* d_out, int out_size, void* d_ws, size_t ws_size,
                              hipStream_t stream)
{
    const float* h_t     = (const float*)d_in[0];
    const float* h_ctx   = (const float*)d_in[1];
    const float* sent    = (const float*)d_in[2];
    const int*   slot_ids= (const int*)  d_in[3];
    const float* memory  = (const float*)d_in[4];
    const float* W_ih    = (const float*)d_in[5];
    const float* W_hh    = (const float*)d_in[6];
    const float* b_ih    = (const float*)d_in[7];
    const float* b_hh    = (const float*)d_in[8];
    const float* W_e     = (const float*)d_in[9];
    const float* b_e     = (const float*)d_in[10];
    const float* W_s     = (const float*)d_in[11];
    const float* b_s     = (const float*)d_in[12];

    float* out       = (float*)d_out;
    float* out_emo   = out;                                    // [B,7]
    float* out_shift = out + (size_t)B_SZ * E_SZ;              // [B]
    float* out_mem   = out + (size_t)B_SZ * E_SZ + B_SZ;       // [S,H]

    int*    winner = (int*)d_ws;                               // S ints
    ushort* W2f    = (ushort*)((char*)d_ws + (size_t)S_SZ * sizeof(int));

    hipMemsetAsync(winner, 0xFF, (size_t)S_SZ * sizeof(int), stream);   // -1

    pack_w2f_kernel<<<(NFR * NSTEP * 64 + 255) / 256, 256, 0, stream>>>(
        W_ih, W_hh, b_ih, b_hh, W_e, b_e, W_s, b_s, W2f);
    winner_kernel<<<B_SZ / 256, 256, 0, stream>>>(slot_ids, winner);
    fused_kernel<<<B_SZ / 16, 512, 0, stream>>>(
        h_t, h_ctx, sent, slot_ids, memory, W2f, winner, out_emo, out_shift, out_mem);
}